// Round 1
// baseline (754.459 us; speedup 1.0000x reference)
//
#include <hip/hip_runtime.h>
#include <hip/hip_bf16.h>

// Problem constants
#define BB 2
#define FDIM 2048
#define FH 64
#define FW 128
#define NPIX (FH*FW)        // 8192 pixels per (dom,b)
#define NC 19
#define SH 512
#define SW 1024

// Workspace layout (bytes)
#define OFF_SUM   0                         // float sum[2][19][2048]  = 311296 B
#define OFF_SQ    311296                    // float sq[2][19]         = 152 B
#define OFF_CNT   311448                    // uint  cnt[2][19]        = 152 B
#define ZERO_BYTES 311600
#define OFF_LAB   311600                    // uchar labels[2][2][8192]= 32768 B
#define OFF_CENT  344368                    // float cent[19][2048]    = 155648 B
#define OFF_DOTS  500016                    // float dots[57]: [0..18]=dot_s, [19..37]=dot_t, [38..56]=cc
#define OFF_ROW   500244                    // float row[19]

// ---------------------------------------------------------------------------
// Kernel 1: labels via align_corners bilinear downsample + argmax over C.
// Replicates jnp.linspace f32 arithmetic and the reference's exact
// mul/add association so floor()/argmax decisions match.
// ---------------------------------------------------------------------------
__global__ __launch_bounds__(256) void labels_kernel(
    const float* __restrict__ sm_s, const float* __restrict__ sm_t,
    unsigned char* __restrict__ labels, unsigned int* __restrict__ cnt) {
  __shared__ unsigned int lcnt[NC];
  int tid = threadIdx.x;
  if (tid < NC) lcnt[tid] = 0u;
  __syncthreads();

  int idx = blockIdx.x * 256 + tid;        // 0..32767
  int dom = idx >> 14;                     // 16384 per domain
  int rem = idx & 16383;
  int b   = rem >> 13;                     // 8192 per batch
  int pix = rem & (NPIX - 1);
  int oy  = pix >> 7;                      // /FW
  int ox  = pix & (FW - 1);

  const float* sm = dom ? sm_t : sm_s;

  const float step_y = 511.0f / 63.0f;     // f32, same as jnp.linspace delta
  const float step_x = 1023.0f / 127.0f;
  float fy = __fmul_rn((float)oy, step_y);
  float fx = __fmul_rn((float)ox, step_x);
  int y0 = (int)floorf(fy); int y1 = min(y0 + 1, SH - 1);
  int x0 = (int)floorf(fx); int x1 = min(x0 + 1, SW - 1);
  float wy = __fsub_rn(fy, (float)y0);
  float wx = __fsub_rn(fx, (float)x0);
  float omwy = __fsub_rn(1.0f, wy);
  float omwx = __fsub_rn(1.0f, wx);

  const float* base = sm + (size_t)b * (NC * SH * SW);
  float best = -1.0f; int bestc = 0;
  for (int c = 0; c < NC; ++c) {
    const float* p = base + (size_t)c * (SH * SW);
    float v00 = p[y0 * SW + x0];
    float v01 = p[y0 * SW + x1];
    float v10 = p[y1 * SW + x0];
    float v11 = p[y1 * SW + x1];
    // r = v_y0*(1-wy) + v_y1*wy ; val = r_x0*(1-wx) + r_x1*wx   (exact ref order)
    float r0  = __fadd_rn(__fmul_rn(v00, omwy), __fmul_rn(v10, wy));
    float r1  = __fadd_rn(__fmul_rn(v01, omwy), __fmul_rn(v11, wy));
    float val = __fadd_rn(__fmul_rn(r0, omwx), __fmul_rn(r1, wx));
    if (val > best) { best = val; bestc = c; }   // strict > == first-max (jnp.argmax)
  }
  labels[idx] = (unsigned char)bestc;
  atomicAdd(&lcnt[bestc], 1u);
  __syncthreads();
  if (tid < NC) atomicAdd(&cnt[dom * NC + tid], lcnt[tid]);  // block is dom-uniform
}

// ---------------------------------------------------------------------------
// Kernel 2 (hot): per-class feature sums S[d][c][f] and per-class Sq[d][c].
// One block per (dom, f): reads 2 coalesced float4 planes + uchar4 labels.
// Per-wave LDS accumulators (native ds_add_f32 via unsafeAtomicAdd).
// ---------------------------------------------------------------------------
__global__ __launch_bounds__(256) void segsum_kernel(
    const float* __restrict__ feat_s, const float* __restrict__ feat_t,
    const unsigned char* __restrict__ labels,
    float* __restrict__ sum, float* __restrict__ sq) {
  __shared__ float lsum[4][20];
  __shared__ float lsq[4][20];
  int tid = threadIdx.x;
  int wave = tid >> 6;
  if (tid < 80) { ((float*)lsum)[tid] = 0.0f; ((float*)lsq)[tid] = 0.0f; }
  __syncthreads();

  int dom = blockIdx.x >> 11;              // 2048 f per domain
  int f   = blockIdx.x & (FDIM - 1);
  const float* feat = dom ? feat_t : feat_s;
  const uchar4* lab4 = (const uchar4*)(labels + dom * (BB * NPIX));
  float* ls = lsum[wave];
  float* lq = lsq[wave];

  for (int b = 0; b < BB; ++b) {
    const float4* src = (const float4*)(feat + ((size_t)b * FDIM + f) * NPIX);
    const uchar4* lb  = lab4 + b * (NPIX / 4);
#pragma unroll
    for (int it = 0; it < 8; ++it) {
      int q = it * 256 + tid;              // float4 index within plane
      float4 v = src[q];
      uchar4 l = lb[q];
      unsafeAtomicAdd(&ls[l.x], v.x); unsafeAtomicAdd(&lq[l.x], v.x * v.x);
      unsafeAtomicAdd(&ls[l.y], v.y); unsafeAtomicAdd(&lq[l.y], v.y * v.y);
      unsafeAtomicAdd(&ls[l.z], v.z); unsafeAtomicAdd(&lq[l.z], v.z * v.z);
      unsafeAtomicAdd(&ls[l.w], v.w); unsafeAtomicAdd(&lq[l.w], v.w * v.w);
    }
  }
  __syncthreads();
  if (tid < NC) {
    float s  = lsum[0][tid] + lsum[1][tid] + lsum[2][tid] + lsum[3][tid];
    float qv = lsq[0][tid]  + lsq[1][tid]  + lsq[2][tid]  + lsq[3][tid];
    sum[((size_t)dom * NC + tid) * FDIM + f] = s;          // unique (d,c,f) -> plain store
    unsafeAtomicAdd(&sq[dom * NC + tid], qv);              // 4096-way low contention
  }
}

// Block reduction helper (256 threads)
__device__ inline float block_reduce(float v, float* red, int tid) {
  red[tid] = v; __syncthreads();
  for (int s = 128; s > 0; s >>= 1) {
    if (tid < s) red[tid] += red[tid + s];
    __syncthreads();
  }
  float r = red[0];
  __syncthreads();
  return r;
}

// ---------------------------------------------------------------------------
// Kernel 3a: centroids[c][f] = (S_s + S_t)/max(cnt,1); also per-class
// dot_s = cent.S_s, dot_t = cent.S_t, cc = |cent|^2.
// ---------------------------------------------------------------------------
__global__ __launch_bounds__(256) void centroid_kernel(
    const float* __restrict__ sum, const unsigned int* __restrict__ cnt,
    float* __restrict__ cent, float* __restrict__ dots) {
  __shared__ float red[256];
  int c = blockIdx.x;
  int tid = threadIdx.x;
  float cs = (float)cnt[c];
  float ct = (float)cnt[NC + c];
  float denom = fmaxf(cs + ct, 1.0f);
  float ds = 0.f, dt = 0.f, cc = 0.f;
  for (int f = tid; f < FDIM; f += 256) {
    float ssv = sum[(size_t)c * FDIM + f];
    float stv = sum[(size_t)(NC + c) * FDIM + f];
    float cf = (ssv + stv) / denom;
    cent[(size_t)c * FDIM + f] = cf;
    ds += cf * ssv; dt += cf * stv; cc += cf * cf;
  }
  float rds = block_reduce(ds, red, tid);
  float rdt = block_reduce(dt, red, tid);
  float rcc = block_reduce(cc, red, tid);
  if (tid == 0) {
    dots[c] = rds;
    dots[NC + c] = rdt;
    dots[2 * NC + c] = rcc;
  }
}

// ---------------------------------------------------------------------------
// Kernel 3b: row[i] = sum_{j != i, seen i&j} sum_f (c_i - c_j)^2
// ---------------------------------------------------------------------------
__global__ __launch_bounds__(256) void pair_kernel(
    const float* __restrict__ cent, const unsigned int* __restrict__ cnt,
    float* __restrict__ row) {
  __shared__ float red[256];
  int i = blockIdx.x;
  int tid = threadIdx.x;
  bool seen_i = (cnt[i] + cnt[NC + i]) > 0u;
  float acc = 0.f;
  if (seen_i) {
    for (int j = 0; j < NC; ++j) {
      if (j == i) continue;
      if ((cnt[j] + cnt[NC + j]) == 0u) continue;
      for (int f = tid; f < FDIM; f += 256) {
        float d = cent[(size_t)i * FDIM + f] - cent[(size_t)j * FDIM + f];
        acc += d * d;
      }
    }
  }
  float r = block_reduce(acc, red, tid);
  if (tid == 0) row[i] = r;
}

// ---------------------------------------------------------------------------
// Kernel 3c: assemble the 3 outputs (p == 2).
// ---------------------------------------------------------------------------
__global__ void final_kernel(
    const unsigned int* __restrict__ cnt, const float* __restrict__ sq,
    const float* __restrict__ dots, const float* __restrict__ row,
    float* __restrict__ out) {
  if (blockIdx.x != 0 || threadIdx.x != 0) return;
  const float fdim = (float)FDIM;
  int nseen = 0;
  for (int c = 0; c < NC; ++c)
    if (cnt[c] + cnt[NC + c] > 0u) nseen++;
  float nseenf = (float)nseen;

  float c_dist = 0.f, fs = 0.f, ft = 0.f;
  int nvs = 0, nvt = 0;
  for (int c = 0; c < NC; ++c) {
    float cs = (float)cnt[c];
    float ct = (float)cnt[NC + c];
    float cc = dots[2 * NC + c];
    if (cs > 0.f) {
      float ssq = sq[c] - 2.0f * dots[c] + cs * cc;
      ssq = fmaxf(ssq, 0.f);
      fs += sqrtf(ssq) / (cs * fdim);
      nvs++;
    }
    if (ct > 0.f) {
      float ssq = sq[NC + c] - 2.0f * dots[NC + c] + ct * cc;
      ssq = fmaxf(ssq, 0.f);
      ft += sqrtf(ssq) / (ct * fdim);
      nvt++;
    }
    if (cs + ct > 0.f) {
      c_dist += sqrtf(row[c]) / ((nseenf - 1.0f) * fdim);
    }
  }
  out[0] = c_dist / nseenf;
  out[1] = fs / (float)nvs;
  out[2] = ft / (float)nvt;
}

extern "C" void kernel_launch(void* const* d_in, const int* in_sizes, int n_in,
                              void* d_out, int out_size, void* d_ws, size_t ws_size,
                              hipStream_t stream) {
  const float* sfeat = (const float*)d_in[0];
  const float* ssm   = (const float*)d_in[1];
  const float* tfeat = (const float*)d_in[2];
  const float* tsm   = (const float*)d_in[3];
  float* out = (float*)d_out;

  char* ws = (char*)d_ws;
  float*         sum    = (float*)(ws + OFF_SUM);
  float*         sq     = (float*)(ws + OFF_SQ);
  unsigned int*  cnt    = (unsigned int*)(ws + OFF_CNT);
  unsigned char* labels = (unsigned char*)(ws + OFF_LAB);
  float*         cent   = (float*)(ws + OFF_CENT);
  float*         dots   = (float*)(ws + OFF_DOTS);
  float*         row    = (float*)(ws + OFF_ROW);

  // zero the accumulators (harness poisons ws once; graph replays need this)
  hipMemsetAsync(ws, 0, ZERO_BYTES, stream);

  labels_kernel  <<<128,  256, 0, stream>>>(ssm, tsm, labels, cnt);
  segsum_kernel  <<<4096, 256, 0, stream>>>(sfeat, tfeat, labels, sum, sq);
  centroid_kernel<<<NC,   256, 0, stream>>>(sum, cnt, cent, dots);
  pair_kernel    <<<NC,   256, 0, stream>>>(cent, cnt, row);
  final_kernel   <<<1,    64,  0, stream>>>(cnt, sq, dots, row, out);
}

// Round 2
// 226.958 us; speedup vs baseline: 3.3242x; 3.3242x over previous
//
#include <hip/hip_runtime.h>
#include <hip/hip_bf16.h>

// Problem constants
#define BB 2
#define FDIM 2048
#define FH 64
#define FW 128
#define NPIX (FH*FW)        // 8192 pixels per (dom,b)
#define NC 19
#define SH 512
#define SW 1024

// Workspace layout (bytes)
#define OFF_SUM   0                         // float sum[2][19][2048]  = 311296 B
#define OFF_SQ    311296                    // float sq[2][19]         = 152 B
#define OFF_CNT   311448                    // uint  cnt[2][19]        = 152 B
#define ZERO_BYTES 311600
#define OFF_LAB   311600                    // uchar labels[2][2][8192]= 32768 B
#define OFF_CENT  344368                    // float cent[19][2048]    = 155648 B
#define OFF_DOTS  500016                    // float dots[57]: [0..18]=dot_s, [19..37]=dot_t, [38..56]=cc
#define OFF_ROW   500244                    // float row[19]

// ---------------------------------------------------------------------------
// Kernel 1: labels via align_corners bilinear downsample + argmax over C.
// Replicates jnp.linspace f32 arithmetic and the reference's exact
// mul/add association so floor()/argmax decisions match.
// ---------------------------------------------------------------------------
__global__ __launch_bounds__(256) void labels_kernel(
    const float* __restrict__ sm_s, const float* __restrict__ sm_t,
    unsigned char* __restrict__ labels, unsigned int* __restrict__ cnt) {
  __shared__ unsigned int lcnt[NC];
  int tid = threadIdx.x;
  if (tid < NC) lcnt[tid] = 0u;
  __syncthreads();

  int idx = blockIdx.x * 256 + tid;        // 0..32767
  int dom = idx >> 14;                     // 16384 per domain
  int rem = idx & 16383;
  int b   = rem >> 13;                     // 8192 per batch
  int pix = rem & (NPIX - 1);
  int oy  = pix >> 7;                      // /FW
  int ox  = pix & (FW - 1);

  const float* sm = dom ? sm_t : sm_s;

  const float step_y = 511.0f / 63.0f;     // f32, same as jnp.linspace delta
  const float step_x = 1023.0f / 127.0f;
  float fy = __fmul_rn((float)oy, step_y);
  float fx = __fmul_rn((float)ox, step_x);
  int y0 = (int)floorf(fy); int y1 = min(y0 + 1, SH - 1);
  int x0 = (int)floorf(fx); int x1 = min(x0 + 1, SW - 1);
  float wy = __fsub_rn(fy, (float)y0);
  float wx = __fsub_rn(fx, (float)x0);
  float omwy = __fsub_rn(1.0f, wy);
  float omwx = __fsub_rn(1.0f, wx);

  const float* base = sm + (size_t)b * (NC * SH * SW);
  float best = -1.0f; int bestc = 0;
  for (int c = 0; c < NC; ++c) {
    const float* p = base + (size_t)c * (SH * SW);
    float v00 = p[y0 * SW + x0];
    float v01 = p[y0 * SW + x1];
    float v10 = p[y1 * SW + x0];
    float v11 = p[y1 * SW + x1];
    // r = v_y0*(1-wy) + v_y1*wy ; val = r_x0*(1-wx) + r_x1*wx   (exact ref order)
    float r0  = __fadd_rn(__fmul_rn(v00, omwy), __fmul_rn(v10, wy));
    float r1  = __fadd_rn(__fmul_rn(v01, omwy), __fmul_rn(v11, wy));
    float val = __fadd_rn(__fmul_rn(r0, omwx), __fmul_rn(r1, wx));
    if (val > best) { best = val; bestc = c; }   // strict > == first-max (jnp.argmax)
  }
  labels[idx] = (unsigned char)bestc;
  atomicAdd(&lcnt[bestc], 1u);
  __syncthreads();
  if (tid < NC) atomicAdd(&cnt[dom * NC + tid], lcnt[tid]);  // block is dom-uniform
}

// ---------------------------------------------------------------------------
// Kernel 2 (hot): per-class feature sums S[d][c][f] and per-class Sq[d][c].
// One block per (dom, f). Branchless per-thread REGISTER accumulators
// (compile-time class indexing -> VGPRs, no LDS atomics in the hot loop).
// Epilogue: 64-lane shfl reduce -> 4 wave partials in LDS -> plain stores.
// ---------------------------------------------------------------------------
__global__ __launch_bounds__(256) void segsum_kernel(
    const float* __restrict__ feat_s, const float* __restrict__ feat_t,
    const unsigned char* __restrict__ labels,
    float* __restrict__ sum, float* __restrict__ sq) {
  __shared__ float lsum[4][NC];
  __shared__ float lsq[4][NC];
  int tid = threadIdx.x;
  int wave = tid >> 6;
  int lane = tid & 63;

  int dom = blockIdx.x >> 11;              // 2048 f per domain
  int f   = blockIdx.x & (FDIM - 1);
  const float* feat = dom ? feat_t : feat_s;
  const uchar4* lab4 = (const uchar4*)(labels + dom * (BB * NPIX));

  float accS[NC], accQ[NC];
#pragma unroll
  for (int c = 0; c < NC; ++c) { accS[c] = 0.0f; accQ[c] = 0.0f; }

  for (int b = 0; b < BB; ++b) {
    const float4* src = (const float4*)(feat + ((size_t)b * FDIM + f) * NPIX);
    const uchar4* lb  = lab4 + b * (NPIX / 4);
#pragma unroll 2
    for (int it = 0; it < 8; ++it) {
      int q = it * 256 + tid;              // float4 index within plane
      float4 v = src[q];
      uchar4 l = lb[q];
      int lx = l.x, ly = l.y, lz = l.z, lw = l.w;
      float vx2 = v.x * v.x, vy2 = v.y * v.y, vz2 = v.z * v.z, vw2 = v.w * v.w;
#pragma unroll
      for (int c = 0; c < NC; ++c) {
        float mx = (lx == c) ? 1.0f : 0.0f;
        float my = (ly == c) ? 1.0f : 0.0f;
        float mz = (lz == c) ? 1.0f : 0.0f;
        float mw = (lw == c) ? 1.0f : 0.0f;
        accS[c] += mx * v.x;  accQ[c] += mx * vx2;
        accS[c] += my * v.y;  accQ[c] += my * vy2;
        accS[c] += mz * v.z;  accQ[c] += mz * vz2;
        accS[c] += mw * v.w;  accQ[c] += mw * vw2;
      }
    }
  }

  // wave-level reduce: lane 0 of each wave gets the wave total per class
#pragma unroll
  for (int c = 0; c < NC; ++c) {
    float s = accS[c], q = accQ[c];
#pragma unroll
    for (int off = 32; off > 0; off >>= 1) {
      s += __shfl_down(s, off, 64);
      q += __shfl_down(q, off, 64);
    }
    if (lane == 0) { lsum[wave][c] = s; lsq[wave][c] = q; }
  }
  __syncthreads();
  if (tid < NC) {
    float s  = lsum[0][tid] + lsum[1][tid] + lsum[2][tid] + lsum[3][tid];
    float qv = lsq[0][tid]  + lsq[1][tid]  + lsq[2][tid]  + lsq[3][tid];
    sum[((size_t)dom * NC + tid) * FDIM + f] = s;          // unique (d,c,f) -> plain store
    unsafeAtomicAdd(&sq[dom * NC + tid], qv);              // 2048 adds per address, pipelined
  }
}

// Block reduction helper (256 threads)
__device__ inline float block_reduce(float v, float* red, int tid) {
  red[tid] = v; __syncthreads();
  for (int s = 128; s > 0; s >>= 1) {
    if (tid < s) red[tid] += red[tid + s];
    __syncthreads();
  }
  float r = red[0];
  __syncthreads();
  return r;
}

// ---------------------------------------------------------------------------
// Kernel 3a: centroids[c][f] = (S_s + S_t)/max(cnt,1); also per-class
// dot_s = cent.S_s, dot_t = cent.S_t, cc = |cent|^2.
// ---------------------------------------------------------------------------
__global__ __launch_bounds__(256) void centroid_kernel(
    const float* __restrict__ sum, const unsigned int* __restrict__ cnt,
    float* __restrict__ cent, float* __restrict__ dots) {
  __shared__ float red[256];
  int c = blockIdx.x;
  int tid = threadIdx.x;
  float cs = (float)cnt[c];
  float ct = (float)cnt[NC + c];
  float denom = fmaxf(cs + ct, 1.0f);
  float ds = 0.f, dt = 0.f, cc = 0.f;
  for (int f = tid; f < FDIM; f += 256) {
    float ssv = sum[(size_t)c * FDIM + f];
    float stv = sum[(size_t)(NC + c) * FDIM + f];
    float cf = (ssv + stv) / denom;
    cent[(size_t)c * FDIM + f] = cf;
    ds += cf * ssv; dt += cf * stv; cc += cf * cf;
  }
  float rds = block_reduce(ds, red, tid);
  float rdt = block_reduce(dt, red, tid);
  float rcc = block_reduce(cc, red, tid);
  if (tid == 0) {
    dots[c] = rds;
    dots[NC + c] = rdt;
    dots[2 * NC + c] = rcc;
  }
}

// ---------------------------------------------------------------------------
// Kernel 3b: row[i] = sum_{j != i, seen i&j} sum_f (c_i - c_j)^2
// ---------------------------------------------------------------------------
__global__ __launch_bounds__(256) void pair_kernel(
    const float* __restrict__ cent, const unsigned int* __restrict__ cnt,
    float* __restrict__ row) {
  __shared__ float red[256];
  int i = blockIdx.x;
  int tid = threadIdx.x;
  bool seen_i = (cnt[i] + cnt[NC + i]) > 0u;
  float acc = 0.f;
  if (seen_i) {
    for (int j = 0; j < NC; ++j) {
      if (j == i) continue;
      if ((cnt[j] + cnt[NC + j]) == 0u) continue;
      for (int f = tid; f < FDIM; f += 256) {
        float d = cent[(size_t)i * FDIM + f] - cent[(size_t)j * FDIM + f];
        acc += d * d;
      }
    }
  }
  float r = block_reduce(acc, red, tid);
  if (tid == 0) row[i] = r;
}

// ---------------------------------------------------------------------------
// Kernel 3c: assemble the 3 outputs (p == 2).
// ---------------------------------------------------------------------------
__global__ void final_kernel(
    const unsigned int* __restrict__ cnt, const float* __restrict__ sq,
    const float* __restrict__ dots, const float* __restrict__ row,
    float* __restrict__ out) {
  if (blockIdx.x != 0 || threadIdx.x != 0) return;
  const float fdim = (float)FDIM;
  int nseen = 0;
  for (int c = 0; c < NC; ++c)
    if (cnt[c] + cnt[NC + c] > 0u) nseen++;
  float nseenf = (float)nseen;

  float c_dist = 0.f, fs = 0.f, ft = 0.f;
  int nvs = 0, nvt = 0;
  for (int c = 0; c < NC; ++c) {
    float cs = (float)cnt[c];
    float ct = (float)cnt[NC + c];
    float cc = dots[2 * NC + c];
    if (cs > 0.f) {
      float ssq = sq[c] - 2.0f * dots[c] + cs * cc;
      ssq = fmaxf(ssq, 0.f);
      fs += sqrtf(ssq) / (cs * fdim);
      nvs++;
    }
    if (ct > 0.f) {
      float ssq = sq[NC + c] - 2.0f * dots[NC + c] + ct * cc;
      ssq = fmaxf(ssq, 0.f);
      ft += sqrtf(ssq) / (ct * fdim);
      nvt++;
    }
    if (cs + ct > 0.f) {
      c_dist += sqrtf(row[c]) / ((nseenf - 1.0f) * fdim);
    }
  }
  out[0] = c_dist / nseenf;
  out[1] = fs / (float)nvs;
  out[2] = ft / (float)nvt;
}

extern "C" void kernel_launch(void* const* d_in, const int* in_sizes, int n_in,
                              void* d_out, int out_size, void* d_ws, size_t ws_size,
                              hipStream_t stream) {
  const float* sfeat = (const float*)d_in[0];
  const float* ssm   = (const float*)d_in[1];
  const float* tfeat = (const float*)d_in[2];
  const float* tsm   = (const float*)d_in[3];
  float* out = (float*)d_out;

  char* ws = (char*)d_ws;
  float*         sum    = (float*)(ws + OFF_SUM);
  float*         sq     = (float*)(ws + OFF_SQ);
  unsigned int*  cnt    = (unsigned int*)(ws + OFF_CNT);
  unsigned char* labels = (unsigned char*)(ws + OFF_LAB);
  float*         cent   = (float*)(ws + OFF_CENT);
  float*         dots   = (float*)(ws + OFF_DOTS);
  float*         row    = (float*)(ws + OFF_ROW);

  // zero the accumulators (harness poisons ws once; graph replays need this)
  hipMemsetAsync(ws, 0, ZERO_BYTES, stream);

  labels_kernel  <<<128,  256, 0, stream>>>(ssm, tsm, labels, cnt);
  segsum_kernel  <<<4096, 256, 0, stream>>>(sfeat, tfeat, labels, sum, sq);
  centroid_kernel<<<NC,   256, 0, stream>>>(sum, cnt, cent, dots);
  pair_kernel    <<<NC,   256, 0, stream>>>(cent, cnt, row);
  final_kernel   <<<1,    64,  0, stream>>>(cnt, sq, dots, row, out);
}

// Round 3
// 155.072 us; speedup vs baseline: 4.8652x; 1.4636x over previous
//
#include <hip/hip_runtime.h>
#include <hip/hip_bf16.h>

// Problem constants
#define BB 2
#define FDIM 2048
#define FH 64
#define FW 128
#define NPIX (FH*FW)        // 8192 pixels per (dom,b)
#define NC 19
#define SH 512
#define SW 1024

// Workspace layout (bytes). Only sq+cnt need zeroing (sum is fully overwritten).
#define OFF_SQ    0                         // float sq[2][19]         = 152 B
#define OFF_CNT   152                       // uint  cnt[2][19]        = 152 B
#define ZERO_BYTES 304
#define OFF_SUM   512                       // float sum[2][19][2048]  = 311296 B
#define OFF_LAB   311808                    // uchar labels[2][2][8192]= 32768 B
#define OFF_CENT  344576                    // float cent[19][2048]    = 155648 B
#define OFF_DOTS  500224                    // float dots[57]
#define OFF_ROW   500452                    // float row[19]

// ---------------------------------------------------------------------------
// Kernel 1: labels via align_corners bilinear downsample + argmax over C.
// 4 lanes per output pixel (5/5/5/4 channels each), shfl_xor argmax merge
// with first-max (lowest class index) tie-break. Replicates jnp.linspace
// f32 arithmetic and the reference's mul/add association exactly.
// ---------------------------------------------------------------------------
__global__ __launch_bounds__(256) void labels_kernel(
    const float* __restrict__ sm_s, const float* __restrict__ sm_t,
    unsigned char* __restrict__ labels, unsigned int* __restrict__ cnt) {
  __shared__ unsigned int lcnt[NC];
  int tid = threadIdx.x;
  if (tid < NC) lcnt[tid] = 0u;
  __syncthreads();

  int g = blockIdx.x * 256 + tid;          // 0..131071
  int pixid = g >> 2;                      // 0..32767
  int sub = g & 3;
  int dom = pixid >> 14;                   // block-uniform (64 pixels/block)
  int rem = pixid & 16383;
  int b   = rem >> 13;
  int pix = rem & (NPIX - 1);
  int oy  = pix >> 7;
  int ox  = pix & (FW - 1);

  const float* sm = dom ? sm_t : sm_s;

  const float step_y = 511.0f / 63.0f;     // f32, same as jnp.linspace delta
  const float step_x = 1023.0f / 127.0f;
  float fy = __fmul_rn((float)oy, step_y);
  float fx = __fmul_rn((float)ox, step_x);
  int y0 = (int)floorf(fy); int y1 = min(y0 + 1, SH - 1);
  int x0 = (int)floorf(fx); int x1 = min(x0 + 1, SW - 1);
  float wy = __fsub_rn(fy, (float)y0);
  float wx = __fsub_rn(fx, (float)x0);
  float omwy = __fsub_rn(1.0f, wy);
  float omwx = __fsub_rn(1.0f, wx);

  const float* base = sm + (size_t)b * (NC * SH * SW);
  float best = -1.0f; int bestc = 127;
  for (int c = sub; c < NC; c += 4) {
    const float* p = base + (size_t)c * (SH * SW);
    float v00 = p[y0 * SW + x0];
    float v01 = p[y0 * SW + x1];
    float v10 = p[y1 * SW + x0];
    float v11 = p[y1 * SW + x1];
    float r0  = __fadd_rn(__fmul_rn(v00, omwy), __fmul_rn(v10, wy));
    float r1  = __fadd_rn(__fmul_rn(v01, omwy), __fmul_rn(v11, wy));
    float val = __fadd_rn(__fmul_rn(r0, omwx), __fmul_rn(r1, wx));
    if (val > best) { best = val; bestc = c; }   // strict > == first-max in subset
  }
  // merge 4-lane group (lanes of one pixel are consecutive)
#pragma unroll
  for (int off = 1; off <= 2; off <<= 1) {
    float ov = __shfl_xor(best, off, 64);
    int   oc = __shfl_xor(bestc, off, 64);
    if (ov > best || (ov == best && oc < bestc)) { best = ov; bestc = oc; }
  }
  if (sub == 0) {
    labels[pixid] = (unsigned char)bestc;
    atomicAdd(&lcnt[bestc], 1u);
  }
  __syncthreads();
  if (tid < NC) atomicAdd(&cnt[dom * NC + tid], lcnt[tid]);  // block is dom-uniform
}

// ---------------------------------------------------------------------------
// Kernel 2 (hot): per-class feature sums S[d][c][f] and per-class Sq[d][c].
// One block per (dom, f). Per-THREAD private LDS accumulators acc[tid][c] =
// (S, Q): one ds_read_b64 + add/fmac + ds_write_b64 per element. No atomics,
// no per-class masking. LDS ops are in-order per wave -> RMW is safe.
// Epilogue: 152 threads each sum 32 rows of one class (in-place partials),
// then 19 threads sum 8 partials -> global store + one f32 atomic for Sq.
// ---------------------------------------------------------------------------
__global__ __launch_bounds__(256) void segsum_kernel(
    const float* __restrict__ feat_s, const float* __restrict__ feat_t,
    const unsigned char* __restrict__ labels,
    float* __restrict__ sum, float* __restrict__ sq) {
  __shared__ float2 acc[256][NC];          // 38912 B -> 4 blocks/CU
  int tid = threadIdx.x;

  float2* myacc = acc[tid];
#pragma unroll
  for (int c = 0; c < NC; ++c) myacc[c] = make_float2(0.0f, 0.0f);
  // no barrier: region is thread-private until the epilogue

  int dom = blockIdx.x >> 11;              // 2048 f per domain
  int f   = blockIdx.x & (FDIM - 1);
  const float* feat = dom ? feat_t : feat_s;
  const uchar4* lab4 = (const uchar4*)(labels + dom * (BB * NPIX));

  for (int b = 0; b < BB; ++b) {
    const float4* __restrict__ src = (const float4*)(feat + ((size_t)b * FDIM + f) * NPIX);
    const uchar4* __restrict__ lb  = lab4 + b * (NPIX / 4);
#pragma unroll 4
    for (int it = 0; it < 8; ++it) {
      int q = it * 256 + tid;              // float4 index within plane (coalesced)
      float4 v = src[q];
      uchar4 l = lb[q];
      { float2 p = myacc[l.x]; p.x += v.x; p.y = fmaf(v.x, v.x, p.y); myacc[l.x] = p; }
      { float2 p = myacc[l.y]; p.x += v.y; p.y = fmaf(v.y, v.y, p.y); myacc[l.y] = p; }
      { float2 p = myacc[l.z]; p.x += v.z; p.y = fmaf(v.z, v.z, p.y); myacc[l.z] = p; }
      { float2 p = myacc[l.w]; p.x += v.w; p.y = fmaf(v.w, v.w, p.y); myacc[l.w] = p; }
    }
  }
  __syncthreads();

  // stage 1: thread (c = tid>>3, j = tid&7) sums rows j*32..j*32+31 of class c,
  // stores partial in-place at acc[j*32][c]. k start staggered by j to spread banks.
  if (tid < NC * 8) {
    int c = tid >> 3, j = tid & 7;
    float s = 0.0f, qv = 0.0f;
#pragma unroll 8
    for (int k = 0; k < 32; ++k) {
      int kk = (k + j * 4) & 31;
      float2 p = acc[j * 32 + kk][c];
      s += p.x; qv += p.y;
    }
    acc[j * 32][c] = make_float2(s, qv);   // row j*32 col c: no cross-thread overlap
  }
  __syncthreads();

  if (tid < NC) {
    float s = 0.0f, qv = 0.0f;
#pragma unroll
    for (int j = 0; j < 8; ++j) {
      float2 p = acc[j * 32][tid];
      s += p.x; qv += p.y;
    }
    sum[((size_t)dom * NC + tid) * FDIM + f] = s;   // unique (d,c,f) -> plain store
    unsafeAtomicAdd(&sq[dom * NC + tid], qv);       // 2048 adds/address, pipelined
  }
}

// Block reduction helper (256 threads)
__device__ inline float block_reduce(float v, float* red, int tid) {
  red[tid] = v; __syncthreads();
  for (int s = 128; s > 0; s >>= 1) {
    if (tid < s) red[tid] += red[tid + s];
    __syncthreads();
  }
  float r = red[0];
  __syncthreads();
  return r;
}

// ---------------------------------------------------------------------------
// Kernel 3a: centroids[c][f] = (S_s + S_t)/max(cnt,1); also per-class
// dot_s = cent.S_s, dot_t = cent.S_t, cc = |cent|^2.
// ---------------------------------------------------------------------------
__global__ __launch_bounds__(256) void centroid_kernel(
    const float* __restrict__ sum, const unsigned int* __restrict__ cnt,
    float* __restrict__ cent, float* __restrict__ dots) {
  __shared__ float red[256];
  int c = blockIdx.x;
  int tid = threadIdx.x;
  float cs = (float)cnt[c];
  float ct = (float)cnt[NC + c];
  float denom = fmaxf(cs + ct, 1.0f);
  float ds = 0.f, dt = 0.f, cc = 0.f;
  for (int f = tid; f < FDIM; f += 256) {
    float ssv = sum[(size_t)c * FDIM + f];
    float stv = sum[(size_t)(NC + c) * FDIM + f];
    float cf = (ssv + stv) / denom;
    cent[(size_t)c * FDIM + f] = cf;
    ds += cf * ssv; dt += cf * stv; cc += cf * cf;
  }
  float rds = block_reduce(ds, red, tid);
  float rdt = block_reduce(dt, red, tid);
  float rcc = block_reduce(cc, red, tid);
  if (tid == 0) {
    dots[c] = rds;
    dots[NC + c] = rdt;
    dots[2 * NC + c] = rcc;
  }
}

// ---------------------------------------------------------------------------
// Kernel 3b: row[i] = sum_{j != i, seen i&j} sum_f (c_i - c_j)^2
// ---------------------------------------------------------------------------
__global__ __launch_bounds__(256) void pair_kernel(
    const float* __restrict__ cent, const unsigned int* __restrict__ cnt,
    float* __restrict__ row) {
  __shared__ float red[256];
  int i = blockIdx.x;
  int tid = threadIdx.x;
  bool seen_i = (cnt[i] + cnt[NC + i]) > 0u;
  float acc = 0.f;
  if (seen_i) {
    for (int j = 0; j < NC; ++j) {
      if (j == i) continue;
      if ((cnt[j] + cnt[NC + j]) == 0u) continue;
      for (int f = tid; f < FDIM; f += 256) {
        float d = cent[(size_t)i * FDIM + f] - cent[(size_t)j * FDIM + f];
        acc += d * d;
      }
    }
  }
  float r = block_reduce(acc, red, tid);
  if (tid == 0) row[i] = r;
}

// ---------------------------------------------------------------------------
// Kernel 3c: assemble the 3 outputs (p == 2).
// ---------------------------------------------------------------------------
__global__ void final_kernel(
    const unsigned int* __restrict__ cnt, const float* __restrict__ sq,
    const float* __restrict__ dots, const float* __restrict__ row,
    float* __restrict__ out) {
  if (blockIdx.x != 0 || threadIdx.x != 0) return;
  const float fdim = (float)FDIM;
  int nseen = 0;
  for (int c = 0; c < NC; ++c)
    if (cnt[c] + cnt[NC + c] > 0u) nseen++;
  float nseenf = (float)nseen;

  float c_dist = 0.f, fs = 0.f, ft = 0.f;
  int nvs = 0, nvt = 0;
  for (int c = 0; c < NC; ++c) {
    float cs = (float)cnt[c];
    float ct = (float)cnt[NC + c];
    float cc = dots[2 * NC + c];
    if (cs > 0.f) {
      float ssq = sq[c] - 2.0f * dots[c] + cs * cc;
      ssq = fmaxf(ssq, 0.f);
      fs += sqrtf(ssq) / (cs * fdim);
      nvs++;
    }
    if (ct > 0.f) {
      float ssq = sq[NC + c] - 2.0f * dots[NC + c] + ct * cc;
      ssq = fmaxf(ssq, 0.f);
      ft += sqrtf(ssq) / (ct * fdim);
      nvt++;
    }
    if (cs + ct > 0.f) {
      c_dist += sqrtf(row[c]) / ((nseenf - 1.0f) * fdim);
    }
  }
  out[0] = c_dist / nseenf;
  out[1] = fs / (float)nvs;
  out[2] = ft / (float)nvt;
}

extern "C" void kernel_launch(void* const* d_in, const int* in_sizes, int n_in,
                              void* d_out, int out_size, void* d_ws, size_t ws_size,
                              hipStream_t stream) {
  const float* sfeat = (const float*)d_in[0];
  const float* ssm   = (const float*)d_in[1];
  const float* tfeat = (const float*)d_in[2];
  const float* tsm   = (const float*)d_in[3];
  float* out = (float*)d_out;

  char* ws = (char*)d_ws;
  float*         sq     = (float*)(ws + OFF_SQ);
  unsigned int*  cnt    = (unsigned int*)(ws + OFF_CNT);
  float*         sum    = (float*)(ws + OFF_SUM);
  unsigned char* labels = (unsigned char*)(ws + OFF_LAB);
  float*         cent   = (float*)(ws + OFF_CENT);
  float*         dots   = (float*)(ws + OFF_DOTS);
  float*         row    = (float*)(ws + OFF_ROW);

  // zero only sq+cnt (sum is fully overwritten; labels fully written)
  hipMemsetAsync(ws, 0, ZERO_BYTES, stream);

  labels_kernel  <<<512,  256, 0, stream>>>(ssm, tsm, labels, cnt);
  segsum_kernel  <<<4096, 256, 0, stream>>>(sfeat, tfeat, labels, sum, sq);
  centroid_kernel<<<NC,   256, 0, stream>>>(sum, cnt, cent, dots);
  pair_kernel    <<<NC,   256, 0, stream>>>(cent, cnt, row);
  final_kernel   <<<1,    64,  0, stream>>>(cnt, sq, dots, row, out);
}